// Round 6
// baseline (430.332 us; speedup 1.0000x reference)
//
#include <hip/hip_runtime.h>
#include <hip/hip_cooperative_groups.h>
#include <math.h>
namespace cg = cooperative_groups;

#define IFACE_ 471
#define CDIM_ 727
#define TC 2181   // 3*CDIM
#define IND 256

// ---- output offsets (floats) ----
#define O_Y   0
#define O_MN  16384
#define O_UN  2113536
#define O_LN  2146304
#define O_WPN 18923520
#define O_WRN 18956288
#define O_WW  19087360
#define O_HC  19120128

// ---- workspace offsets (floats) ----
#define P1_STRIDE 279168     // 128*2181
#define WS_P1   0            // 16*279168
#define WS_FWD  0            // aliases P1 (dead after GRU)
#define WS_SIM  131072
#define WS_BWDP 262144       // 64*8*2048
#define WS_P2   4466688      // 12*65536
#define P2_STRIDE 65536
#define WS_C    5253120      // 128*727
#define WS_PAR  5346176      // 64*512

// ---- per-batch param layout (stride 512) ----
#define PK_NKW 0
#define PK_ER  64
#define PK_WV  128
#define PK_NKR 192
#define PK_BR  448
#define PK_MOD 452
#define PK_BW  464
#define PK_AG  465
#define PK_WG  466
#define PK_FG  468

__device__ __forceinline__ float sigf(float x){ return 1.f/(1.f+expf(-x)); }
__device__ __forceinline__ float softplusf(float x){ return (x>20.f)? x : log1pf(expf(x)); }
__device__ __forceinline__ float geluf(float x){ return 0.5f*x*(1.f+erff(x*0.70710678118654752440f)); }
__device__ __forceinline__ float dot4(float4 a, float4 b){ return a.x*b.x+a.y*b.y+a.z*b.z+a.w*b.w; }
__device__ __forceinline__ void fma4(float4& a, float s, float4 v){ a.x+=s*v.x; a.y+=s*v.y; a.z+=s*v.z; a.w+=s*v.w; }
__device__ __forceinline__ float4 ln_combine(float4 l4, float4 wwj, float4 wpj, float base, float wwi){
  float4 r;
  r.x = (base - wwj.x)*l4.x + wwi*wpj.x;
  r.y = (base - wwj.y)*l4.y + wwi*wpj.y;
  r.z = (base - wwj.z)*l4.z + wwi*wpj.z;
  r.w = (base - wwj.w)*l4.w + wwi*wpj.w;
  return r;
}
__device__ __forceinline__ void diag_zero(float4& r, int d){
  if (d==0) r.x=0.f; else if (d==1) r.y=0.f; else if (d==2) r.z=0.f; else if (d==3) r.w=0.f;
}

// ================= broadcast GEMM body: 64 rows x 64 cols x K<=64, 512 thr =================
__device__ void phase_gemm(const float* __restrict__ A, int lda, int K,
                           const float* __restrict__ B, int ldb, int Ncols,
                           float* __restrict__ C, int ldc,
                           int k0, int klen, int n0, int t, float* As)
{
  __syncthreads();   // protect As reuse
  for (int i = t; i < 4096; i += 512) {
    int m = i >> 6, kk = i & 63;
    As[i] = (kk < klen) ? A[m*lda + k0 + kk] : 0.f;
  }
  __syncthreads();
  int c = n0 + (t & 63);
  int cc = (c < Ncols) ? c : 0;
  int m0 = (t >> 6) * 8;
  float acc[8];
  #pragma unroll
  for (int r = 0; r < 8; r++) acc[r] = 0.f;
  const float* Bc = B + cc;
  for (int kk = 0; kk < 64; kk += 4) {
    int r0 = k0 + kk;
    int i0 = min(r0+0, K-1), i1 = min(r0+1, K-1), i2 = min(r0+2, K-1), i3 = min(r0+3, K-1);
    float b0 = Bc[(size_t)i0*ldb];
    float b1 = Bc[(size_t)i1*ldb];
    float b2 = Bc[(size_t)i2*ldb];
    float b3 = Bc[(size_t)i3*ldb];
    const float* ap = As + kk;
    #pragma unroll
    for (int r = 0; r < 8; r++) {
      float4 a4 = *(const float4*)&ap[(m0+r)*64];
      acc[r] += a4.x*b0 + a4.y*b1 + a4.z*b2 + a4.w*b3;
    }
  }
  if (c < Ncols) {
    float* Cp = C + c;
    #pragma unroll
    for (int r = 0; r < 8; r++) Cp[(size_t)(m0+r)*ldc] = acc[r];
  }
}

__device__ void phase_p1(int task, const float* xin, const float* hprev,
                         const float* gk, const float* grk, float* P1p, int t, float* sm)
{
  int nt = task % 35;
  int sz = task / 35;
  int s = sz & 15, rh = sz >> 4;
  const float* A; const float* B; int lda, K, k0, klen;
  if (s < 4) { A = xin + rh*64*IND;    lda = IND;   B = gk;  K = IND;   k0 = s*64;     klen = 64; }
  else       { A = hprev + rh*64*CDIM_; lda = CDIM_; B = grk; K = CDIM_; k0 = (s-4)*61; klen = (s==15)?56:61; }
  phase_gemm(A, lda, K, B, TC, TC,
             P1p + (size_t)s*P1_STRIDE + (size_t)rh*64*TC, TC, k0, klen, nt*64, t, sm);
}

__device__ void phase_p3(int task, const float* cbuf, const float* Wif, float* P2p, int t, float* sm)
{
  int nt = task & 7;
  int s = (task >> 3) % 12;
  int rh = task / 96;
  int k0 = s*61, klen = (s==11)?56:61;
  phase_gemm(cbuf + rh*64*CDIM_, CDIM_, CDIM_, Wif, IFACE_, IFACE_,
             P2p + (size_t)s*P2_STRIDE + (size_t)rh*64*512, 512, k0, klen, nt*64, t, sm);
}

__device__ void phase_gru(int idx, const float* P1p, const float* hprev,
                          const float* gbias, float* cbuf, float* out)
{
  int p = idx / CDIM_, u = idx % CDIM_;
  float zs=0.f, rs=0.f, xh=0.f, rh2=0.f;
  #pragma unroll
  for (int s = 0; s < 16; s++) {
    const float* Ps = P1p + (size_t)s*P1_STRIDE + (size_t)p*TC;
    zs += Ps[u]; rs += Ps[CDIM_+u];
    float hv = Ps[2*CDIM_+u];
    if (s < 4) xh += hv; else rh2 += hv;
  }
  zs += gbias[u] + gbias[TC+u];
  rs += gbias[CDIM_+u] + gbias[TC+CDIM_+u];
  xh += gbias[2*CDIM_+u];
  rh2 += gbias[TC+2*CDIM_+u];
  float z_ = sigf(zs);
  float r_ = sigf(rs);
  float hh = geluf(xh + r_*rh2);
  float h  = hprev[(size_t)p*CDIM_ + u];
  float cv = z_*h + (1.f - z_)*hh;
  cbuf[(size_t)p*CDIM_ + u] = cv;
  out[O_HC + (size_t)p*CDIM_ + u] = cv;
}

// sm pool usage: [0..511] ifr, [512..1023] ifw, [1024..1535] su, [1536..2047] si,
// [2048..2559] alloc, [2560..2623] nkw, [2624..2627] fg, [2628..2635] wredA,
// [2636..2643] wredB, [2644..2651] warpTot, [2652..2654] scalars(bw,ag,wg)
__device__ void phase_small(int b, int t, float* sm,
    const float* P2p, const float* Min, const float* usage,
    const float* W_read, const float* W_write, const float* Wp,
    float* out, float* params)
{
  float* ifr = sm;            float* ifw = sm + 512;
  float* su  = sm + 1024;     int*   si  = (int*)(sm + 1536);
  float* alloc_l = sm + 2048; float* s_nkw = sm + 2560;
  float* s_fg = sm + 2624;    float* wredA = sm + 2628;
  float* wredB = sm + 2636;   float* warpTot = sm + 2644;
  float* s_scal = sm + 2652;  // [bw, ag, wg]
  int lane = t & 63, wid = t >> 6;
  float* pp = params + b*512;

  if (t < IFACE_) {
    float sr = 0.f, sw = 0.f;
    #pragma unroll
    for (int s = 0; s < 12; s++) {
      const float* base = P2p + (size_t)s*P2_STRIDE;
      sr += base[(b*2+0)*512 + t];
      sw += base[(b*2+1)*512 + t];
    }
    ifr[t] = sr; ifw[t] = sw;
  }
  __syncthreads();

  if (t < 64) {
    float ss = 0.f;
    for (int w = 0; w < 64; w++) { float v = ifw[260+w]; ss += v*v; }
    float rn = rsqrtf(fmaxf(ss, 1e-12f));
    float nk = ifw[260+t]*rn;
    pp[PK_NKW + t] = nk; s_nkw[t] = nk;
    pp[PK_ER  + t] = sigf(ifw[325+t]);
    pp[PK_WV  + t] = ifw[389+t];
  } else if (t < 320) {
    int r = (t-64) >> 6, w = (t-64) & 63;
    float ss = 0.f;
    for (int w2 = 0; w2 < 64; w2++) { float v = ifr[r*64+w2]; ss += v*v; }
    pp[PK_NKR + r*64 + w] = ifr[r*64+w]*rsqrtf(fmaxf(ss, 1e-12f));
  } else if (t < 324) {
    pp[PK_BR + (t-320)] = 1.f + softplusf(ifr[256 + (t-320)]);
  } else if (t < 336) {
    int i = t-324; int mm = i >> 2, r = i & 3;
    float v0 = ifr[459+r], v1 = ifr[459+4+r], v2 = ifr[459+8+r];
    float mx = fmaxf(v0, fmaxf(v1, v2));
    float e0 = expf(v0-mx), e1 = expf(v1-mx), e2 = expf(v2-mx);
    float den = e0+e1+e2;
    pp[PK_MOD + i] = (mm==0 ? e0 : (mm==1 ? e1 : e2)) / den;
  } else if (t == 336) { float v = 1.f + softplusf(ifw[324]); pp[PK_BW] = v; s_scal[0] = v; }
  else if (t == 337) { float v = sigf(ifw[457]); pp[PK_AG] = v; s_scal[1] = v; }
  else if (t == 338) { float v = sigf(ifw[458]); pp[PK_WG] = v; s_scal[2] = v; }
  else if (t < 343) { int r = t-339; float v = sigf(ifw[453+r]); pp[PK_FG+r] = v; s_fg[r] = v; }
  __syncthreads();

  float un;
  {
    float4 wr4 = *(const float4*)&W_read[(size_t)(b*512+t)*4];
    float ret = (1.f - s_fg[0]*wr4.x)*(1.f - s_fg[1]*wr4.y)*(1.f - s_fg[2]*wr4.z)*(1.f - s_fg[3]*wr4.w);
    float u = usage[b*512+t], w = W_write[b*512+t];
    un = (u + w - u*w)*ret;
    out[O_UN + b*512 + t] = un;
  }

  float v = un; int key = t;
  for (int k = 2; k <= 512; k <<= 1) {
    for (int j = k >> 1; j > 0; j >>= 1) {
      bool dir = ((t & k) == 0);
      if (j >= 64) {
        su[t] = v; si[t] = key;
        __syncthreads();
        float pv = su[t ^ j]; int pi = si[t ^ j];
        bool gt = (v > pv) || (v == pv && key > pi);
        bool take = ((t & j) == 0) ? (gt == dir) : (gt != dir);
        if (take) { v = pv; key = pi; }
        __syncthreads();
      } else {
        float pv = __shfl_xor(v, j);
        int   pi = __shfl_xor(key, j);
        bool gt = (v > pv) || (v == pv && key > pi);
        bool take = ((t & j) == 0) ? (gt == dir) : (gt != dir);
        if (take) { v = pv; key = pi; }
      }
    }
  }

  {
    float x = v;
    #pragma unroll
    for (int off = 1; off < 64; off <<= 1) {
      float y = __shfl_up(x, off);
      if (lane >= off) x *= y;
    }
    if (lane == 63) warpTot[wid] = x;
    __syncthreads();
    float pre = 1.f;
    for (int w2 = 0; w2 < wid; w2++) pre *= warpTot[w2];
    float xm1 = __shfl_up(x, 1);
    float excl = (lane == 0) ? pre : pre*xm1;
    alloc_l[key] = (1.f - v)*excl;
  }
  __syncthreads();

  float mysim;
  {
    const float* mrow = Min + (size_t)(b*512+t)*64;
    float ss = 0.f, dt = 0.f;
    #pragma unroll
    for (int i = 0; i < 16; i++) {
      float4 m4 = *(const float4*)&mrow[i*4];
      float4 k4 = *(const float4*)&s_nkw[i*4];
      ss += dot4(m4, m4); dt += dot4(m4, k4);
    }
    mysim = dt * rsqrtf(fmaxf(ss, 1e-12f)) * s_scal[0];
  }
  float mw = mysim;
  #pragma unroll
  for (int off = 32; off > 0; off >>= 1) mw = fmaxf(mw, __shfl_xor(mw, off));
  if (lane == 0) wredA[wid] = mw;
  __syncthreads();
  float mx = wredA[0];
  #pragma unroll
  for (int i = 1; i < 8; i++) mx = fmaxf(mx, wredA[i]);
  float e = expf(mysim - mx);
  float sw_ = e;
  #pragma unroll
  for (int off = 32; off > 0; off >>= 1) sw_ += __shfl_xor(sw_, off);
  if (lane == 0) wredB[wid] = sw_;
  __syncthreads();
  float den = 0.f;
  #pragma unroll
  for (int i = 0; i < 8; i++) den += wredB[i];
  float lkp = e / den;

  float s_ag = s_scal[1], s_wg = s_scal[2];
  float ww = s_wg * (s_ag * alloc_l[t] + (1.f - s_ag) * lkp);
  out[O_WW + b*512 + t] = ww;
  float wsum = ww;
  #pragma unroll
  for (int off = 32; off > 0; off >>= 1) wsum += __shfl_xor(wsum, off);
  if (lane == 0) wredA[wid] = wsum;
  __syncthreads();
  float sum = 0.f;
  #pragma unroll
  for (int i = 0; i < 8; i++) sum += wredA[i];

  out[O_WPN + b*512 + t] = (1.f - sum)*Wp[b*512+t] + ww;
}

// sm pool: [0..511] wwl, [512..1023] wpl, [1024..3071] wrT[r*512+n],
// [3072..11263] wbuf[4][2048], [11264..11327] sER, [11328..11391] sWV,
// [11392..11647] sNKR, [11648..11651] sBR     (total 11712 floats = 46.8 KB)
__device__ void phase_ln(int task, int t, float* sm,
    const float* L, const float* Wp, const float* W_read, const float* Min,
    const float* params, float* out, float* fwd, float* bwdp, float* sims)
{
  float* wwl = sm;            float* wpl = sm + 512;
  float* wrT = sm + 1024;     float* wbuf = sm + 3072;
  float* sER = sm + 11264;    float* sWV = sm + 11328;
  float* sNKR = sm + 11392;   float* sBR = sm + 11648;
  int b = task >> 3, it = task & 7, i0 = it*64;
  int lane = t & 63, wid = t >> 6;
  const float* pp = params + b*512;

  __syncthreads();   // protect reuse across task loop
  {
    int n = t;
    wwl[n] = out[O_WW + b*512 + n];
    wpl[n] = Wp[b*512 + n];
    float4 w4 = *(const float4*)&W_read[(size_t)(b*512+n)*4];
    wrT[n] = w4.x; wrT[512+n] = w4.y; wrT[1024+n] = w4.z; wrT[1536+n] = w4.w;
  }
  if (t < 64)        sER[t]      = pp[PK_ER + t];
  else if (t < 128)  sWV[t-64]   = pp[PK_WV + (t-64)];
  else if (t < 132)  sBR[t-128]  = pp[PK_BR + (t-128)];
  else if (t >= 256) sNKR[t-256] = pp[PK_NKR + (t-256)];
  __syncthreads();

  // fused M_n + sims (8 threads per row)
  {
    int mrow = t >> 3, mq = t & 7;
    int gr = i0 + mrow;
    float ww = wwl[gr];
    const float* Mr = Min + (size_t)(b*512+gr)*64 + mq*8;
    float* MNr = out + O_MN + (size_t)(b*512+gr)*64 + mq*8;
    float ss=0.f, d0=0.f, d1=0.f, d2=0.f, d3=0.f;
    #pragma unroll
    for (int i = 0; i < 2; i++) {
      int c = mq*8 + i*4;
      float4 m4 = *(const float4*)&Mr[i*4];
      float4 er = *(const float4*)&sER[c];
      float4 wv = *(const float4*)&sWV[c];
      float4 r;
      r.x = m4.x*(1.f - ww*er.x) + ww*wv.x;
      r.y = m4.y*(1.f - ww*er.y) + ww*wv.y;
      r.z = m4.z*(1.f - ww*er.z) + ww*wv.z;
      r.w = m4.w*(1.f - ww*er.w) + ww*wv.w;
      *(float4*)&MNr[i*4] = r;
      ss += dot4(r, r);
      d0 += dot4(r, *(const float4*)&sNKR[      c]);
      d1 += dot4(r, *(const float4*)&sNKR[ 64 + c]);
      d2 += dot4(r, *(const float4*)&sNKR[128 + c]);
      d3 += dot4(r, *(const float4*)&sNKR[192 + c]);
    }
    #pragma unroll
    for (int m = 1; m < 8; m <<= 1) {
      ss += __shfl_xor(ss, m);
      d0 += __shfl_xor(d0, m); d1 += __shfl_xor(d1, m);
      d2 += __shfl_xor(d2, m); d3 += __shfl_xor(d3, m);
    }
    if (mq == 0) {
      float rn = rsqrtf(fmaxf(ss, 1e-12f));
      float4 s;
      s.x = d0*rn*sBR[0]; s.y = d1*rn*sBR[1];
      s.z = d2*rn*sBR[2]; s.w = d3*rn*sBR[3];
      *(float4*)&sims[(size_t)(b*512+gr)*4] = s;
    }
  }

  // main loop: 8 waves x 8 rows, full 512 cols per row
  int jb0 = lane*4, jb1 = 256 + lane*4;
  float4 ww0 = *(const float4*)&wwl[jb0], ww1 = *(const float4*)&wwl[jb1];
  float4 wp0 = *(const float4*)&wpl[jb0], wp1 = *(const float4*)&wpl[jb1];
  float4 wr0[4], wr1[4], b0[4], b1[4];
  #pragma unroll
  for (int rr = 0; rr < 4; rr++) {
    wr0[rr] = *(const float4*)&wrT[rr*512 + jb0];
    wr1[rr] = *(const float4*)&wrT[rr*512 + jb1];
    b0[rr] = make_float4(0.f,0.f,0.f,0.f);
    b1[rr] = make_float4(0.f,0.f,0.f,0.f);
  }
  const float* Lb  = L + (size_t)b*262144;
  float* LNb = out + O_LN + (size_t)b*262144;
  #pragma unroll 2
  for (int ri = 0; ri < 8; ri++) {
    int gi = i0 + wid*8 + ri;
    float wwi = wwl[gi], base = 1.f - wwi;
    float wi0 = wrT[gi], wi1 = wrT[512+gi], wi2 = wrT[1024+gi], wi3 = wrT[1536+gi];
    const float* lrow = Lb + (size_t)gi*512;
    float* orow = LNb + (size_t)gi*512;
    float4 l0 = *(const float4*)&lrow[jb0];
    float4 l1 = *(const float4*)&lrow[jb1];
    float4 r0 = ln_combine(l0, ww0, wp0, base, wwi);
    diag_zero(r0, gi - jb0);
    float4 r1 = ln_combine(l1, ww1, wp1, base, wwi);
    diag_zero(r1, gi - jb1);
    *(float4*)&orow[jb0] = r0;
    *(float4*)&orow[jb1] = r1;
    float f0 = dot4(r0, wr0[0]) + dot4(r1, wr1[0]);
    float f1 = dot4(r0, wr0[1]) + dot4(r1, wr1[1]);
    float f2 = dot4(r0, wr0[2]) + dot4(r1, wr1[2]);
    float f3 = dot4(r0, wr0[3]) + dot4(r1, wr1[3]);
    fma4(b0[0], wi0, r0); fma4(b0[1], wi1, r0); fma4(b0[2], wi2, r0); fma4(b0[3], wi3, r0);
    fma4(b1[0], wi0, r1); fma4(b1[1], wi1, r1); fma4(b1[2], wi2, r1); fma4(b1[3], wi3, r1);
    float s1 = (lane & 1) ? f0 : f1;
    float p  = ((lane & 1) ? f1 : f0) + __shfl_xor(s1, 1);
    float s2 = (lane & 1) ? f2 : f3;
    float q  = ((lane & 1) ? f3 : f2) + __shfl_xor(s2, 1);
    float s3 = (lane & 2) ? p : q;
    float w  = ((lane & 2) ? q : p) + __shfl_xor(s3, 2);
    #pragma unroll
    for (int off = 4; off < 64; off <<= 1) w += __shfl_xor(w, off);
    if (lane < 4) fwd[(size_t)(b*512+gi)*4 + lane] = w;
  }

  // cross-wave bwd reduce: waves 0-3 store, waves 4-7 add, then 4-buffer sum -> slot
  if (wid < 4) {
    float* wb = wbuf + wid*2048;
    #pragma unroll
    for (int rr = 0; rr < 4; rr++) {
      *(float4*)&wb[rr*512 + jb0] = b0[rr];
      *(float4*)&wb[rr*512 + jb1] = b1[rr];
    }
  }
  __syncthreads();
  if (wid >= 4) {
    float* wb = wbuf + (wid-4)*2048;
    #pragma unroll
    for (int rr = 0; rr < 4; rr++) {
      float4 v0 = *(const float4*)&wb[rr*512 + jb0];
      v0.x += b0[rr].x; v0.y += b0[rr].y; v0.z += b0[rr].z; v0.w += b0[rr].w;
      *(float4*)&wb[rr*512 + jb0] = v0;
      float4 v1 = *(const float4*)&wb[rr*512 + jb1];
      v1.x += b1[rr].x; v1.y += b1[rr].y; v1.z += b1[rr].z; v1.w += b1[rr].w;
      *(float4*)&wb[rr*512 + jb1] = v1;
    }
  }
  __syncthreads();
  float* slot = bwdp + (size_t)(b*8 + it)*2048;
  #pragma unroll
  for (int q2 = 0; q2 < 4; q2++) {
    int o = t + q2*512;
    int j = o >> 2, rr = o & 3;
    int a = rr*512 + j;
    slot[o] = wbuf[a] + wbuf[2048+a] + wbuf[4096+a] + wbuf[6144+a];
  }
}

// ======================= cooperative fused kernel =======================
__global__ __launch_bounds__(512, 2) void k_fused(
    const float* __restrict__ xin, const float* __restrict__ Min,
    const float* __restrict__ usage, const float* __restrict__ L,
    const float* __restrict__ Wp, const float* __restrict__ W_read,
    const float* __restrict__ W_write, const float* __restrict__ hprev,
    const float* __restrict__ Wif, const float* __restrict__ gk,
    const float* __restrict__ grk, const float* __restrict__ gbias,
    float* __restrict__ out, float* __restrict__ ws)
{
  cg::grid_group grid = cg::this_grid();
  __shared__ float sm[11712];
  int t = threadIdx.x;

  for (int task = blockIdx.x; task < 1120; task += gridDim.x)
    phase_p1(task, xin, hprev, gk, grk, ws + WS_P1, t, sm);
  grid.sync();

  for (int idx = blockIdx.x*512 + t; idx < 128*CDIM_; idx += gridDim.x*512)
    phase_gru(idx, ws + WS_P1, hprev, gbias, ws + WS_C, out);
  grid.sync();

  for (int task = blockIdx.x; task < 192; task += gridDim.x)
    phase_p3(task, ws + WS_C, Wif, ws + WS_P2, t, sm);
  grid.sync();

  if (blockIdx.x < 64)
    phase_small(blockIdx.x, t, sm, ws + WS_P2, Min, usage, W_read, W_write, Wp,
                out, ws + WS_PAR);
  grid.sync();

  for (int task = blockIdx.x; task < 512; task += gridDim.x)
    phase_ln(task, t, sm, L, Wp, W_read, Min, ws + WS_PAR, out,
             ws + WS_FWD, ws + WS_BWDP, ws + WS_SIM);
}

// ======================= fallback kernels =======================
__global__ __launch_bounds__(512) void k_p1(const float* __restrict__ xin,
    const float* __restrict__ hprev, const float* __restrict__ gk,
    const float* __restrict__ grk, float* __restrict__ P1p)
{
  __shared__ float sm[4096];
  phase_p1(blockIdx.x, xin, hprev, gk, grk, P1p, threadIdx.x, sm);
}

__global__ __launch_bounds__(512) void k_p2(const float* __restrict__ P1p,
    const float* __restrict__ hprev, const float* __restrict__ gbias,
    float* __restrict__ cbuf, float* __restrict__ out)
{
  int idx = blockIdx.x*512 + threadIdx.x;
  if (idx < 128*CDIM_) phase_gru(idx, P1p, hprev, gbias, cbuf, out);
}

__global__ __launch_bounds__(512) void k_p3(const float* __restrict__ cbuf,
    const float* __restrict__ Wif, float* __restrict__ P2p)
{
  __shared__ float sm[4096];
  phase_p3(blockIdx.x, cbuf, Wif, P2p, threadIdx.x, sm);
}

__global__ __launch_bounds__(512) void k_p4(const float* __restrict__ P2p,
    const float* __restrict__ Min, const float* __restrict__ usage,
    const float* __restrict__ W_read, const float* __restrict__ W_write,
    const float* __restrict__ Wp, float* __restrict__ out, float* __restrict__ params)
{
  __shared__ float sm[2688];
  phase_small(blockIdx.x, threadIdx.x, sm, P2p, Min, usage, W_read, W_write, Wp, out, params);
}

__global__ __launch_bounds__(512) void k_p5(const float* __restrict__ L,
    const float* __restrict__ Wp, const float* __restrict__ W_read,
    const float* __restrict__ Min, const float* __restrict__ params,
    float* __restrict__ out, float* __restrict__ fwd,
    float* __restrict__ bwdp, float* __restrict__ sims)
{
  __shared__ float sm[11712];
  phase_ln(blockIdx.x, threadIdx.x, sm, L, Wp, W_read, Min, params, out, fwd, bwdp, sims);
}

// ======================= lookup softmax + Wr_n + read_v + y =======================
__global__ __launch_bounds__(1024) void k_final(const float* __restrict__ fwd,
    const float* __restrict__ bwdp, const float* __restrict__ sims,
    const float* __restrict__ params, const float* __restrict__ Wro,
    float* __restrict__ out)
{
  __shared__ float wrl[2048];
  __shared__ float buf[1024];
  __shared__ float rv[256];
  __shared__ float mo[12];
  __shared__ float4 redm[8], reds[8];
  int b = blockIdx.x, t = threadIdx.x;
  int lane = t & 63, wid = t >> 6;
  const float* pp = params + b*512;
  if (t < 12) mo[t] = pp[PK_MOD + t];

  float4 s4 = make_float4(0.f,0.f,0.f,0.f);
  if (t < 512) {
    s4 = *(const float4*)&sims[(size_t)(b*512+t)*4];
    float4 m4 = s4;
    #pragma unroll
    for (int off = 32; off > 0; off >>= 1) {
      m4.x = fmaxf(m4.x, __shfl_xor(m4.x, off));
      m4.y = fmaxf(m4.y, __shfl_xor(m4.y, off));
      m4.z = fmaxf(m4.z, __shfl_xor(m4.z, off));
      m4.w = fmaxf(m4.w, __shfl_xor(m4.w, off));
    }
    if (lane == 0) redm[wid] = m4;
  }
  __syncthreads();
  float4 e4 = make_float4(0.f,0.f,0.f,0.f);
  if (t < 512) {
    float4 mx = redm[0];
    #pragma unroll
    for (int i = 1; i < 8; i++) {
      mx.x = fmaxf(mx.x, redm[i].x); mx.y = fmaxf(mx.y, redm[i].y);
      mx.z = fmaxf(mx.z, redm[i].z); mx.w = fmaxf(mx.w, redm[i].w);
    }
    e4.x = expf(s4.x - mx.x); e4.y = expf(s4.y - mx.y);
    e4.z = expf(s4.z - mx.z); e4.w = expf(s4.w - mx.w);
    float4 t4 = e4;
    #pragma unroll
    for (int off = 32; off > 0; off >>= 1) {
      t4.x += __shfl_xor(t4.x, off); t4.y += __shfl_xor(t4.y, off);
      t4.z += __shfl_xor(t4.z, off); t4.w += __shfl_xor(t4.w, off);
    }
    if (lane == 0) reds[wid] = t4;
  }
  __syncthreads();
  if (t < 512) {
    float4 dn = reds[0];
    #pragma unroll
    for (int i = 1; i < 8; i++) { dn.x += reds[i].x; dn.y += reds[i].y; dn.z += reds[i].z; dn.w += reds[i].w; }
    float4 lk; lk.x = e4.x/dn.x; lk.y = e4.y/dn.y; lk.z = e4.z/dn.z; lk.w = e4.w/dn.w;
    size_t o = (size_t)(b*512 + t)*4;
    float4 f4 = *(const float4*)&fwd[o];
    float4 b4 = make_float4(0.f,0.f,0.f,0.f);
    #pragma unroll
    for (int it = 0; it < 8; it++) {
      float4 p4 = *(const float4*)&bwdp[(size_t)(b*8+it)*2048 + t*4];
      b4.x += p4.x; b4.y += p4.y; b4.z += p4.z; b4.w += p4.w;
    }
    float4 w;
    w.x = mo[0]*b4.x + mo[4]*lk.x + mo[8] *f4.x;
    w.y = mo[1]*b4.y + mo[5]*lk.y + mo[9] *f4.y;
    w.z = mo[2]*b4.z + mo[6]*lk.z + mo[10]*f4.z;
    w.w = mo[3]*b4.w + mo[7]*lk.w + mo[11]*f4.w;
    *(float4*)&out[O_WRN + o] = w;
    *(float4*)&wrl[t*4] = w;
  }
  __syncthreads();

  {
    int w = lane, r = wid & 3, n4 = t >> 8;
    const float* mnb = out + O_MN + (size_t)b*32768 + w;
    float acc = 0.f;
    int nb = n4*128;
    #pragma unroll 4
    for (int n = nb; n < nb + 128; n++) acc += wrl[n*4 + r] * mnb[(size_t)n*64];
    buf[t] = acc;
  }
  __syncthreads();
  if (t < 256) rv[t] = buf[t] + buf[t+256] + buf[t+512] + buf[t+768];
  __syncthreads();

  {
    int o = t & 255, k4 = t >> 8;
    float acc = 0.f;
    #pragma unroll 4
    for (int k = k4*64; k < k4*64 + 64; k++) acc += rv[k] * Wro[k*256 + o];
    buf[t] = acc;
  }
  __syncthreads();
  if (t < 256) out[O_Y + b*256 + t] = buf[t] + buf[t+256] + buf[t+512] + buf[t+768];
}

// ======================= launch =======================
extern "C" void kernel_launch(void* const* d_in, const int* in_sizes, int n_in,
                              void* d_out, int out_size, void* d_ws, size_t ws_size,
                              hipStream_t stream)
{
  const float* inputs  = (const float*)d_in[0];
  const float* M       = (const float*)d_in[1];
  const float* usage   = (const float*)d_in[2];
  const float* L       = (const float*)d_in[3];
  const float* Wp      = (const float*)d_in[4];
  const float* W_read  = (const float*)d_in[5];
  const float* W_write = (const float*)d_in[6];
  const float* h_ctrl  = (const float*)d_in[7];
  const float* W_iface = (const float*)d_in[8];
  const float* W_ro    = (const float*)d_in[9];
  const float* gk      = (const float*)d_in[10];
  const float* grk     = (const float*)d_in[11];
  const float* gb      = (const float*)d_in[12];
  float* out = (float*)d_out;
  float* ws  = (float*)d_ws;

  void* args[] = { (void*)&inputs, (void*)&M, (void*)&usage, (void*)&L,
                   (void*)&Wp, (void*)&W_read, (void*)&W_write, (void*)&h_ctrl,
                   (void*)&W_iface, (void*)&gk, (void*)&grk, (void*)&gb,
                   (void*)&out, (void*)&ws };
  hipError_t err = hipLaunchCooperativeKernel((const void*)k_fused, dim3(256), dim3(512),
                                              args, 0, stream);
  if (err != hipSuccess) {
    (void)hipGetLastError();   // clear error state; fall back to multi-dispatch
    k_p1<<<1120, 512, 0, stream>>>(inputs, h_ctrl, gk, grk, ws + WS_P1);
    k_p2<<<182, 512, 0, stream>>>(ws + WS_P1, h_ctrl, gb, ws + WS_C, out);
    k_p3<<<192, 512, 0, stream>>>(ws + WS_C, W_iface, ws + WS_P2);
    k_p4<<<64, 512, 0, stream>>>(ws + WS_P2, M, usage, W_read, W_write, Wp, out, ws + WS_PAR);
    k_p5<<<512, 512, 0, stream>>>(L, Wp, W_read, M, ws + WS_PAR, out,
                                  ws + WS_FWD, ws + WS_BWDP, ws + WS_SIM);
  }
  k_final<<<64, 1024, 0, stream>>>(ws + WS_FWD, ws + WS_BWDP, ws + WS_SIM,
                                   ws + WS_PAR, W_ro, out);
}

// Round 7
// 357.831 us; speedup vs baseline: 1.2026x; 1.2026x over previous
//
#include <hip/hip_runtime.h>
#include <math.h>

#define IFACE_ 471
#define CDIM_ 727
#define TC 2181   // 3*CDIM
#define IND 256

// ---- output offsets (floats) ----
#define O_Y   0
#define O_MN  16384
#define O_UN  2113536
#define O_LN  2146304
#define O_WPN 18923520
#define O_WRN 18956288
#define O_WW  19087360
#define O_HC  19120128

// ---- workspace offsets (floats) ----
#define WS_CZR  0         // 128 x 1454 = 186112
#define WS_CXH  186112    // 128 x 727  = 93056
#define WS_CRH  279168    // 93056 -> 372224
#define WS_C2   372224    // 128 x 471 iface = 60288 -> 432512
#define WS_C    432512    // cbuf 128 x 727 = 93056 -> 525568
#define WS_PAR  525568    // 64 x 512 = 32768 -> 558336
#define WS_SIM  558336    // 131072 -> 689408
#define WS_FWD  689408    // 2 x 131072 = 262144 -> 951552
#define WS_BWDP 951552    // 64*32*1024 = 2097152 -> 3048704
#define WS_RVP  3048704   // 64*4*256 = 65536 -> 3114240

// ---- per-batch param layout (stride 512) ----
#define PK_NKW 0
#define PK_ER  64
#define PK_WV  128
#define PK_NKR 192
#define PK_BR  448
#define PK_MOD 452
#define PK_BW  464
#define PK_AG  465
#define PK_WG  466
#define PK_FG  468

__device__ __forceinline__ float sigf(float x){ return 1.f/(1.f+expf(-x)); }
__device__ __forceinline__ float softplusf(float x){ return (x>20.f)? x : log1pf(expf(x)); }
__device__ __forceinline__ float geluf(float x){ return 0.5f*x*(1.f+erff(x*0.70710678118654752440f)); }
__device__ __forceinline__ float dot4(float4 a, float4 b){ return a.x*b.x+a.y*b.y+a.z*b.z+a.w*b.w; }
__device__ __forceinline__ void fma4(float4& a, float s, float4 v){ a.x+=s*v.x; a.y+=s*v.y; a.z+=s*v.z; a.w+=s*v.w; }

// =============== GEMM1: mx+mh fused, full-K, no partials ===============
// grid (35, 8): n-tile of 64 over 2181 cols, row-group of 16 over 128 rows.
// Czr[128][1454] = (x@gk + h@grk) for z,r cols; Cxh/Crh[128][727] split for h-gate.
__global__ __launch_bounds__(256) void k_gemm1(const float* __restrict__ xin,
    const float* __restrict__ hprev, const float* __restrict__ gk,
    const float* __restrict__ grk, float* __restrict__ Czr,
    float* __restrict__ Cxh, float* __restrict__ Crh)
{
  __shared__ float As[16*984];   // row-major [m][k], k: 0..255 x-part, 256..982 h-part, 983 pad
  int t = threadIdx.x;
  int n0 = blockIdx.x * 64, m0 = blockIdx.y * 16;
  for (int i = t; i < 4096; i += 256) {          // x part, coalesced
    int m = i >> 8, k = i & 255;
    As[m*984 + k] = xin[(m0+m)*IND + k];
  }
  for (int i = t; i < 11632; i += 256) {         // h part (16*727), coalesced
    int m = i / 727, k = i - m*727;
    As[m*984 + 256 + k] = hprev[(m0+m)*CDIM_ + k];
  }
  if (t < 16) As[t*984 + 983] = 0.f;             // pad col
  __syncthreads();

  int c = n0 + (t & 63);
  int cc = min(c, 2180);
  int rg = t >> 6;
  float accA[4] = {0.f,0.f,0.f,0.f};             // x contribution
  float accB[4] = {0.f,0.f,0.f,0.f};             // h contribution
  const float* gkc = gk + cc;
  for (int k = 0; k < 256; k += 4) {
    float b0 = gkc[(size_t)(k+0)*TC];
    float b1 = gkc[(size_t)(k+1)*TC];
    float b2 = gkc[(size_t)(k+2)*TC];
    float b3 = gkc[(size_t)(k+3)*TC];
    #pragma unroll
    for (int r = 0; r < 4; r++) {
      float4 a = *(const float4*)&As[(rg*4+r)*984 + k];
      accA[r] += a.x*b0 + a.y*b1 + a.z*b2 + a.w*b3;
    }
  }
  const float* grkc = grk + cc;
  for (int k = 0; k < 728; k += 4) {
    float b0 = grkc[(size_t)min(k+0,726)*TC];
    float b1 = grkc[(size_t)min(k+1,726)*TC];
    float b2 = grkc[(size_t)min(k+2,726)*TC];
    float b3 = grkc[(size_t)min(k+3,726)*TC];
    #pragma unroll
    for (int r = 0; r < 4; r++) {
      float4 a = *(const float4*)&As[(rg*4+r)*984 + 256 + k];
      accB[r] += a.x*b0 + a.y*b1 + a.z*b2 + a.w*b3;
    }
  }
  if (c <= 2180) {
    #pragma unroll
    for (int r = 0; r < 4; r++) {
      int row = m0 + rg*4 + r;
      if (c < 1454) Czr[(size_t)row*1454 + c] = accA[r] + accB[r];
      else { Cxh[(size_t)row*727 + (c-1454)] = accA[r];
             Crh[(size_t)row*727 + (c-1454)] = accB[r]; }
    }
  }
}

// =============== GRU pointwise (direct reads, no slice reduction) ===============
__global__ __launch_bounds__(512) void k_gru(const float* __restrict__ Czr,
    const float* __restrict__ Cxh, const float* __restrict__ Crh,
    const float* __restrict__ hprev, const float* __restrict__ gbias,
    float* __restrict__ cbuf, float* __restrict__ out)
{
  int idx = blockIdx.x*512 + threadIdx.x;
  if (idx >= 128*CDIM_) return;
  int p = idx / CDIM_, u = idx - p*CDIM_;
  float zs = Czr[(size_t)p*1454 + u]       + gbias[u]       + gbias[TC+u];
  float rs = Czr[(size_t)p*1454 + 727 + u] + gbias[727+u]   + gbias[TC+727+u];
  float xh = Cxh[(size_t)p*727 + u]        + gbias[1454+u];
  float rh = Crh[(size_t)p*727 + u]        + gbias[TC+1454+u];
  float z_ = sigf(zs);
  float r_ = sigf(rs);
  float hh = geluf(xh + r_*rh);
  float h  = hprev[(size_t)p*CDIM_ + u];
  float cv = z_*h + (1.f - z_)*hh;
  cbuf[(size_t)p*CDIM_ + u] = cv;
  out[O_HC + (size_t)p*CDIM_ + u] = cv;
}

// =============== GEMM2: iface = c @ W_iface, full-K ===============
// grid (8, 16): col-tile of 64 over 471, row-group of 8 over 128.
__global__ __launch_bounds__(256) void k_gemm2(const float* __restrict__ cbuf,
    const float* __restrict__ Wif, float* __restrict__ C2)
{
  __shared__ float As[8*728];
  int t = threadIdx.x;
  int n0 = blockIdx.x * 64, m0 = blockIdx.y * 8;
  for (int i = t; i < 5816; i += 256) {
    int m = i / 727, k = i - m*727;
    As[m*728 + k] = cbuf[(m0+m)*CDIM_ + k];
  }
  if (t < 8) As[t*728 + 727] = 0.f;
  __syncthreads();
  int c = n0 + (t & 63);
  int cc = min(c, 470);
  int rg = t >> 6;
  float acc[2] = {0.f, 0.f};
  const float* wc = Wif + cc;
  for (int k = 0; k < 728; k += 4) {
    float b0 = wc[(size_t)min(k+0,726)*IFACE_];
    float b1 = wc[(size_t)min(k+1,726)*IFACE_];
    float b2 = wc[(size_t)min(k+2,726)*IFACE_];
    float b3 = wc[(size_t)min(k+3,726)*IFACE_];
    #pragma unroll
    for (int r = 0; r < 2; r++) {
      float4 a = *(const float4*)&As[(rg*2+r)*728 + k];
      acc[r] += a.x*b0 + a.y*b1 + a.z*b2 + a.w*b3;
    }
  }
  if (c < 471) {
    #pragma unroll
    for (int r = 0; r < 2; r++)
      C2[(size_t)(m0 + rg*2 + r)*471 + c] = acc[r];
  }
}

// =============== per-batch small ops (direct iface read) ===============
__global__ __launch_bounds__(512) void k_small(
    const float* __restrict__ C2, const float* __restrict__ Min,
    const float* __restrict__ usage, const float* __restrict__ W_read,
    const float* __restrict__ W_write, const float* __restrict__ Wp,
    float* __restrict__ out, float* __restrict__ params)
{
  __shared__ float ifr[IFACE_], ifw[IFACE_];
  __shared__ float su[512]; __shared__ int si[512];
  __shared__ float alloc_l[512];
  __shared__ float s_nkw[64];
  __shared__ float s_fg[4];
  __shared__ float s_bw, s_ag, s_wg;
  __shared__ float wredA[8], wredB[8], warpTot[8];
  int b = blockIdx.x, t = threadIdx.x;
  int lane = t & 63, wid = t >> 6;
  float* pp = params + b*512;

  if (t < IFACE_) {
    ifr[t] = C2[(size_t)(b*2+0)*471 + t];
    ifw[t] = C2[(size_t)(b*2+1)*471 + t];
  }
  __syncthreads();

  if (t < 64) {
    float ss = 0.f;
    for (int w = 0; w < 64; w++) { float v = ifw[260+w]; ss += v*v; }
    float rn = rsqrtf(fmaxf(ss, 1e-12f));
    float nk = ifw[260+t]*rn;
    pp[PK_NKW + t] = nk; s_nkw[t] = nk;
    pp[PK_ER  + t] = sigf(ifw[325+t]);
    pp[PK_WV  + t] = ifw[389+t];
  } else if (t < 320) {
    int r = (t-64) >> 6, w = (t-64) & 63;
    float ss = 0.f;
    for (int w2 = 0; w2 < 64; w2++) { float v = ifr[r*64+w2]; ss += v*v; }
    pp[PK_NKR + r*64 + w] = ifr[r*64+w]*rsqrtf(fmaxf(ss, 1e-12f));
  } else if (t < 324) {
    pp[PK_BR + (t-320)] = 1.f + softplusf(ifr[256 + (t-320)]);
  } else if (t < 336) {
    int i = t-324; int mm = i >> 2, r = i & 3;
    float v0 = ifr[459+r], v1 = ifr[459+4+r], v2 = ifr[459+8+r];
    float mx = fmaxf(v0, fmaxf(v1, v2));
    float e0 = expf(v0-mx), e1 = expf(v1-mx), e2 = expf(v2-mx);
    float den = e0+e1+e2;
    pp[PK_MOD + i] = (mm==0 ? e0 : (mm==1 ? e1 : e2)) / den;
  } else if (t == 336) { float v = 1.f + softplusf(ifw[324]); pp[PK_BW] = v; s_bw = v; }
  else if (t == 337) { float v = sigf(ifw[457]); pp[PK_AG] = v; s_ag = v; }
  else if (t == 338) { float v = sigf(ifw[458]); pp[PK_WG] = v; s_wg = v; }
  else if (t < 343) { int r = t-339; float v = sigf(ifw[453+r]); pp[PK_FG+r] = v; s_fg[r] = v; }
  __syncthreads();

  float un;
  {
    float4 wr4 = *(const float4*)&W_read[(size_t)(b*512+t)*4];
    float ret = (1.f - s_fg[0]*wr4.x)*(1.f - s_fg[1]*wr4.y)*(1.f - s_fg[2]*wr4.z)*(1.f - s_fg[3]*wr4.w);
    float u = usage[b*512+t], w = W_write[b*512+t];
    un = (u + w - u*w)*ret;
    out[O_UN + b*512 + t] = un;
  }

  float v = un; int key = t;
  for (int k = 2; k <= 512; k <<= 1) {
    for (int j = k >> 1; j > 0; j >>= 1) {
      bool dir = ((t & k) == 0);
      if (j >= 64) {
        su[t] = v; si[t] = key;
        __syncthreads();
        float pv = su[t ^ j]; int pi = si[t ^ j];
        bool gt = (v > pv) || (v == pv && key > pi);
        bool take = ((t & j) == 0) ? (gt == dir) : (gt != dir);
        if (take) { v = pv; key = pi; }
        __syncthreads();
      } else {
        float pv = __shfl_xor(v, j);
        int   pi = __shfl_xor(key, j);
        bool gt = (v > pv) || (v == pv && key > pi);
        bool take = ((t & j) == 0) ? (gt == dir) : (gt != dir);
        if (take) { v = pv; key = pi; }
      }
    }
  }

  {
    float x = v;
    #pragma unroll
    for (int off = 1; off < 64; off <<= 1) {
      float y = __shfl_up(x, off);
      if (lane >= off) x *= y;
    }
    if (lane == 63) warpTot[wid] = x;
    __syncthreads();
    float pre = 1.f;
    for (int w2 = 0; w2 < wid; w2++) pre *= warpTot[w2];
    float xm1 = __shfl_up(x, 1);
    float excl = (lane == 0) ? pre : pre*xm1;
    alloc_l[key] = (1.f - v)*excl;
  }
  __syncthreads();

  float mysim;
  {
    const float* mrow = Min + (size_t)(b*512+t)*64;
    float ss = 0.f, dt = 0.f;
    #pragma unroll
    for (int i = 0; i < 16; i++) {
      float4 m4 = *(const float4*)&mrow[i*4];
      float4 k4 = *(const float4*)&s_nkw[i*4];
      ss += dot4(m4, m4); dt += dot4(m4, k4);
    }
    mysim = dt * rsqrtf(fmaxf(ss, 1e-12f)) * s_bw;
  }
  float mw = mysim;
  #pragma unroll
  for (int off = 32; off > 0; off >>= 1) mw = fmaxf(mw, __shfl_xor(mw, off));
  if (lane == 0) wredA[wid] = mw;
  __syncthreads();
  float mx = wredA[0];
  #pragma unroll
  for (int i = 1; i < 8; i++) mx = fmaxf(mx, wredA[i]);
  float e = expf(mysim - mx);
  float sw_ = e;
  #pragma unroll
  for (int off = 32; off > 0; off >>= 1) sw_ += __shfl_xor(sw_, off);
  if (lane == 0) wredB[wid] = sw_;
  __syncthreads();
  float den = 0.f;
  #pragma unroll
  for (int i = 0; i < 8; i++) den += wredB[i];
  float lkp = e / den;

  float ww = s_wg * (s_ag * alloc_l[t] + (1.f - s_ag) * lkp);
  out[O_WW + b*512 + t] = ww;
  float wsum = ww;
  #pragma unroll
  for (int off = 32; off > 0; off >>= 1) wsum += __shfl_xor(wsum, off);
  if (lane == 0) wredA[wid] = wsum;
  __syncthreads();
  float sum = 0.f;
  #pragma unroll
  for (int i = 0; i < 8; i++) sum += wredA[i];

  out[O_WPN + b*512 + t] = (1.f - sum)*Wp[b*512+t] + ww;
}

// =============== L_n + fwd + bwd + M_n + sims — 2048 blocks, no atomics ===============
// grid: bid = b*32 + it*2 + jh.  Block: rows [it*32, +32), cols [jh*256, +256).
__global__ __launch_bounds__(256, 4) void k_ln(const float* __restrict__ L,
    const float* __restrict__ Wp, const float* __restrict__ W_read,
    const float* __restrict__ Min, const float* __restrict__ params,
    float* __restrict__ out, float* __restrict__ fwdp,
    float* __restrict__ bwdp, float* __restrict__ sims)
{
  __shared__ float s_ww[32];
  __shared__ float s_wr[4][32];
  __shared__ float sER[64], sWV[64], sNKR[256], sBR[4];
  __shared__ float wbuf[4096];
  int bid = blockIdx.x;
  int b = bid >> 5, rest = bid & 31, it = rest >> 1, jh = rest & 1;
  int i0 = it*32, j0 = jh*256;
  int t = threadIdx.x, lane = t & 63, wid = t >> 6;
  const float* pp = params + b*512;

  if (t < 32) {
    s_ww[t] = out[O_WW + b*512 + i0 + t];
    float4 w4 = *(const float4*)&W_read[(size_t)(b*512+i0+t)*4];
    s_wr[0][t]=w4.x; s_wr[1][t]=w4.y; s_wr[2][t]=w4.z; s_wr[3][t]=w4.w;
  }
  sNKR[t] = pp[PK_NKR + t];
  if (t >= 64 && t < 128) sER[t-64] = pp[PK_ER + (t-64)];
  else if (t >= 128 && t < 192) sWV[t-128] = pp[PK_WV + (t-128)];
  else if (t >= 192 && t < 196) sBR[t-192] = pp[PK_BR + (t-192)];
  __syncthreads();

  // fused M_n + sims (only jh==0 blocks; 8 threads per row, rows i0..i0+31)
  if (jh == 0) {
    int mrow = t >> 3, mq = t & 7;
    int gr = i0 + mrow;
    float ww = s_ww[mrow];
    const float* Mr = Min + (size_t)(b*512+gr)*64 + mq*8;
    float* MNr = out + O_MN + (size_t)(b*512+gr)*64 + mq*8;
    float ss=0.f, d0=0.f, d1=0.f, d2=0.f, d3=0.f;
    #pragma unroll
    for (int i = 0; i < 2; i++) {
      int c = mq*8 + i*4;
      float4 m4 = *(const float4*)&Mr[i*4];
      float4 er = *(const float4*)&sER[c];
      float4 wv = *(const float4*)&sWV[c];
      float4 r;
      r.x = m4.x*(1.f - ww*er.x) + ww*wv.x;
      r.y = m4.y*(1.f - ww*er.y) + ww*wv.y;
      r.z = m4.z*(1.f - ww*er.z) + ww*wv.z;
      r.w = m4.w*(1.f - ww*er.w) + ww*wv.w;
      *(float4*)&MNr[i*4] = r;
      ss += dot4(r, r);
      d0 += dot4(r, *(const float4*)&sNKR[      c]);
      d1 += dot4(r, *(const float4*)&sNKR[ 64 + c]);
      d2 += dot4(r, *(const float4*)&sNKR[128 + c]);
      d3 += dot4(r, *(const float4*)&sNKR[192 + c]);
    }
    #pragma unroll
    for (int m = 1; m < 8; m <<= 1) {
      ss += __shfl_xor(ss, m);
      d0 += __shfl_xor(d0, m); d1 += __shfl_xor(d1, m);
      d2 += __shfl_xor(d2, m); d3 += __shfl_xor(d3, m);
    }
    if (mq == 0) {
      float rn = rsqrtf(fmaxf(ss, 1e-12f));
      float4 s;
      s.x = d0*rn*sBR[0]; s.y = d1*rn*sBR[1];
      s.z = d2*rn*sBR[2]; s.w = d3*rn*sBR[3];
      *(float4*)&sims[(size_t)(b*512+gr)*4] = s;
    }
  }

  // col-side registers
  int j = j0 + lane*4;
  float4 wwj = *(const float4*)&out[O_WW + b*512 + j];
  float4 wpj = *(const float4*)&Wp[b*512 + j];
  float4 wj0 = *(const float4*)&W_read[(size_t)(b*512+j+0)*4];
  float4 wj1 = *(const float4*)&W_read[(size_t)(b*512+j+1)*4];
  float4 wj2 = *(const float4*)&W_read[(size_t)(b*512+j+2)*4];
  float4 wj3 = *(const float4*)&W_read[(size_t)(b*512+j+3)*4];
  float4 bacc[4];
  #pragma unroll
  for (int r = 0; r < 4; r++) bacc[r] = make_float4(0.f,0.f,0.f,0.f);

  const float* Lb  = L + (size_t)b*262144;
  float* LNb = out + O_LN + (size_t)b*262144;
  #pragma unroll 2
  for (int ri = 0; ri < 8; ri++) {
    int rl = wid*8 + ri;
    int gi = i0 + rl;
    float wwi = s_ww[rl], base = 1.f - wwi;
    float4 l4 = *(const float4*)&Lb[(size_t)gi*512 + j];
    float4 r4;
    r4.x = (base - wwj.x)*l4.x + wwi*wpj.x;
    r4.y = (base - wwj.y)*l4.y + wwi*wpj.y;
    r4.z = (base - wwj.z)*l4.z + wwi*wpj.z;
    r4.w = (base - wwj.w)*l4.w + wwi*wpj.w;
    int d = gi - j;
    if (d == 0) r4.x = 0.f; else if (d == 1) r4.y = 0.f;
    else if (d == 2) r4.z = 0.f; else if (d == 3) r4.w = 0.f;
    *(float4*)&LNb[(size_t)gi*512 + j] = r4;
    float f0 = r4.x*wj0.x + r4.y*wj1.x + r4.z*wj2.x + r4.w*wj3.x;
    float f1 = r4.x*wj0.y + r4.y*wj1.y + r4.z*wj2.y + r4.w*wj3.y;
    float f2 = r4.x*wj0.z + r4.y*wj1.z + r4.z*wj2.z + r4.w*wj3.z;
    float f3 = r4.x*wj0.w + r4.y*wj1.w + r4.z*wj2.w + r4.w*wj3.w;
    fma4(bacc[0], s_wr[0][rl], r4);
    fma4(bacc[1], s_wr[1][rl], r4);
    fma4(bacc[2], s_wr[2][rl], r4);
    fma4(bacc[3], s_wr[3][rl], r4);
    // quad-pack fwd reduce
    float s1 = (lane & 1) ? f0 : f1;
    float p  = ((lane & 1) ? f1 : f0) + __shfl_xor(s1, 1);
    float s2 = (lane & 1) ? f2 : f3;
    float q  = ((lane & 1) ? f3 : f2) + __shfl_xor(s2, 1);
    float s3 = (lane & 2) ? p : q;
    float w  = ((lane & 2) ? q : p) + __shfl_xor(s3, 2);
    #pragma unroll
    for (int off = 4; off < 64; off <<= 1) w += __shfl_xor(w, off);
    if (lane < 4) fwdp[(size_t)jh*131072 + (size_t)(b*512+gi)*4 + lane] = w;
  }

  // cross-wave bwd reduce via LDS, plain store to slot
  #pragma unroll
  for (int r = 0; r < 4; r++)
    *(float4*)&wbuf[wid*1024 + r*256 + lane*4] = bacc[r];
  __syncthreads();
  float* slot = bwdp + ((size_t)(b*2+jh)*16 + it)*1024;
  #pragma unroll
  for (int q2 = 0; q2 < 4; q2++) {
    int o = t + q2*256;
    slot[o] = wbuf[o] + wbuf[1024+o] + wbuf[2048+o] + wbuf[3072+o];
  }
}

// =============== softmax + Wr_n ===============
__global__ __launch_bounds__(512) void k_wrn(const float* __restrict__ fwdp,
    const float* __restrict__ bwdp, const float* __restrict__ sims,
    const float* __restrict__ params, float* __restrict__ out)
{
  __shared__ float mo[12];
  __shared__ float4 redm[8], reds[8];
  int b = blockIdx.x, t = threadIdx.x;
  int lane = t & 63, wid = t >> 6;
  const float* pp = params + b*512;
  if (t < 12) mo[t] = pp[PK_MOD + t];

  float4 s4 = *(const float4*)&sims[(size_t)(b*512+t)*4];
  float4 m4 = s4;
  #pragma unroll
  for (int off = 32; off > 0; off >>= 1) {
    m4.x = fmaxf(m4.x, __shfl_xor(m4.x, off));
    m4.y = fmaxf(m4.y, __shfl_xor(m4.y, off));
    m4.z = fmaxf(m4.z, __shfl_xor(m4.z, off));
    m4.w = fmaxf(m4.w, __shfl_xor(m4.w, off));
  }
  if (lane == 0) redm[wid] = m4;
  __syncthreads();
  float4 mx = redm[0];
  #pragma unroll
  for (int i = 1; i < 8; i++) {
    mx.x = fmaxf(mx.x, redm[i].x); mx.y = fmaxf(mx.y, redm[i].y);
    mx.z = fmaxf(mx.z, redm[i].z); mx.w = fmaxf(mx.w, redm[i].w);
  }
  float4 e4;
  e4.x = expf(s4.x - mx.x); e4.y = expf(s4.y - mx.y);
  e4.z = expf(s4.z - mx.z); e4.w = expf(s4.w - mx.w);
  float4 t4 = e4;
  #pragma unroll
  for (int off = 32; off > 0; off >>= 1) {
    t4.x += __shfl_xor(t4.x, off); t4.y += __shfl_xor(t4.y, off);
    t4.z += __shfl_xor(t4.z, off); t4.w += __shfl_xor(t4.w, off);
  }
  if (lane == 0) reds[wid] = t4;
  __syncthreads();
  float4 dn = reds[0];
  #pragma unroll
  for (int i = 1; i < 8; i++) { dn.x += reds[i].x; dn.y += reds[i].y; dn.z += reds[i].z; dn.w += reds[i].w; }
  float4 lk; lk.x = e4.x/dn.x; lk.y = e4.y/dn.y; lk.z = e4.z/dn.z; lk.w = e4.w/dn.w;

  size_t o = (size_t)(b*512 + t)*4;
  float4 fa = *(const float4*)&fwdp[o];
  float4 fb = *(const float4*)&fwdp[131072 + o];
  float4 f4; f4.x = fa.x+fb.x; f4.y = fa.y+fb.y; f4.z = fa.z+fb.z; f4.w = fa.w+fb.w;

  int jh = t >> 8, cloc = t & 255;
  const float* bp = bwdp + ((size_t)(b*2+jh)*16)*1024;
  float4 b4 = make_float4(0.f,0.f,0.f,0.f);
  #pragma unroll
  for (int it = 0; it < 16; it++) {
    b4.x += bp[it*1024 +       cloc];
    b4.y += bp[it*1024 + 256 + cloc];
    b4.z += bp[it*1024 + 512 + cloc];
    b4.w += bp[it*1024 + 768 + cloc];
  }
  float4 w;
  w.x = mo[0]*b4.x + mo[4]*lk.x + mo[8] *f4.x;
  w.y = mo[1]*b4.y + mo[5]*lk.y + mo[9] *f4.y;
  w.z = mo[2]*b4.z + mo[6]*lk.z + mo[10]*f4.z;
  w.w = mo[3]*b4.w + mo[7]*lk.w + mo[11]*f4.w;
  *(float4*)&out[O_WRN + o] = w;
}

// =============== read_v partials: grid (4 n-quarters, 64 batches) ===============
__global__ __launch_bounds__(256) void k_rv(const float* __restrict__ out,
    float* __restrict__ rvp)
{
  __shared__ float wrl[512];
  int n4 = blockIdx.x, b = blockIdx.y, t = threadIdx.x;
  const float* wsrc = out + O_WRN + (size_t)(b*512 + n4*128)*4;
  wrl[t] = wsrc[t];
  wrl[t+256] = wsrc[t+256];
  __syncthreads();
  int r = t >> 6, w = t & 63;
  const float* mnb = out + O_MN + (size_t)b*32768 + (size_t)n4*128*64 + w;
  float acc = 0.f;
  #pragma unroll 8
  for (int n = 0; n < 128; n++) acc += wrl[n*4 + r] * mnb[(size_t)n*64];
  rvp[(size_t)(b*4 + n4)*256 + t] = acc;
}

// =============== y = rv @ Wro ===============
__global__ __launch_bounds__(256) void k_y(const float* __restrict__ rvp,
    const float* __restrict__ Wro, float* __restrict__ out)
{
  __shared__ float rv[256];
  int b = blockIdx.x, t = threadIdx.x;
  const float* rp = rvp + (size_t)b*4*256;
  rv[t] = rp[t] + rp[256+t] + rp[512+t] + rp[768+t];
  __syncthreads();
  float acc = 0.f;
  #pragma unroll 8
  for (int k = 0; k < 256; k++) acc += rv[k] * Wro[(size_t)k*256 + t];
  out[O_Y + b*256 + t] = acc;
}

// ======================= launch =======================
extern "C" void kernel_launch(void* const* d_in, const int* in_sizes, int n_in,
                              void* d_out, int out_size, void* d_ws, size_t ws_size,
                              hipStream_t stream)
{
  const float* inputs  = (const float*)d_in[0];
  const float* M       = (const float*)d_in[1];
  const float* usage   = (const float*)d_in[2];
  const float* L       = (const float*)d_in[3];
  const float* Wp      = (const float*)d_in[4];
  const float* W_read  = (const float*)d_in[5];
  const float* W_write = (const float*)d_in[6];
  const float* h_ctrl  = (const float*)d_in[7];
  const float* W_iface = (const float*)d_in[8];
  const float* W_ro    = (const float*)d_in[9];
  const float* gk      = (const float*)d_in[10];
  const float* grk     = (const float*)d_in[11];
  const float* gb      = (const float*)d_in[12];
  float* out = (float*)d_out;
  float* ws  = (float*)d_ws;

  k_gemm1<<<dim3(35,8), 256, 0, stream>>>(inputs, h_ctrl, gk, grk,
                                          ws + WS_CZR, ws + WS_CXH, ws + WS_CRH);
  k_gru<<<182, 512, 0, stream>>>(ws + WS_CZR, ws + WS_CXH, ws + WS_CRH,
                                 h_ctrl, gb, ws + WS_C, out);
  k_gemm2<<<dim3(8,16), 256, 0, stream>>>(ws + WS_C, W_iface, ws + WS_C2);
  k_small<<<64, 512, 0, stream>>>(ws + WS_C2, M, usage, W_read, W_write, Wp,
                                  out, ws + WS_PAR);
  k_ln<<<2048, 256, 0, stream>>>(L, Wp, W_read, M, ws + WS_PAR, out,
                                 ws + WS_FWD, ws + WS_BWDP, ws + WS_SIM);
  k_wrn<<<64, 512, 0, stream>>>(ws + WS_FWD, ws + WS_BWDP, ws + WS_SIM,
                                ws + WS_PAR, out);
  k_rv<<<dim3(4,64), 256, 0, stream>>>(out, ws + WS_RVP);
  k_y<<<64, 256, 0, stream>>>(ws + WS_RVP, W_ro, out);
}